// Round 4
// baseline (611.160 us; speedup 1.0000x reference)
//
#include <hip/hip_runtime.h>
#include <hip/hip_bf16.h>
#include <math.h>

// ---------------------------------------------------------------------------
// GCNWithEdge, algebraically folded + CSR gather.
// DTYPES (established R3): ALL float tensors are FP32 on the wire, in AND out.
// Ints are int32.
//   h1 = relu(Anorm @ (x@W1) + b1)                      (full 64-wide, conv1)
//   Q[n][c]  = h1[n] . U[:,c],   U = W2 @ fcW1[0:64,:]  (64->2 projection)
//   P[n][c]  = sum_{e:dst=n} norm*Q[src][c] + dinv^2*Q[n][c]   (CSR gather)
//   z[e][c]  = P[s][c]-P[d][c] + a0*fcW1[64,c] + a1*fcW1[65,c]
//              + E0t[a2][c] + E1t[a3][c] + fcb1[c]
//   (NOTE: conv2's bias b2 cancels in P[s]-P[d] — NOT folded into C.)
//   out = log_softmax( relu(z) @ fcW2 + fcb2 )   -> fp32
// ws ~15.6 MB; edge col list parked in d_out (12.8 MB) until the final kernel.
// ---------------------------------------------------------------------------

typedef __hip_bfloat16 bf16;

// ---------------- degree / CSR build ----------------
__global__ void k_zero(int* __restrict__ a, int N) {
    int i = blockIdx.x * blockDim.x + threadIdx.x;
    if (i < N) a[i] = 0;
}

__global__ void k_hist(const int* __restrict__ dst, int* __restrict__ cnt, int E) {
    int e = blockIdx.x * blockDim.x + threadIdx.x;
    if (e < E) atomicAdd(&cnt[dst[e]], 1);
}

__global__ void k_dinvk(const int* __restrict__ cnt, float* __restrict__ dinv, int N) {
    int i = blockIdx.x * blockDim.x + threadIdx.x;
    if (i < N) dinv[i] = rsqrtf((float)cnt[i] + 1.0f);   // +1 self-loop
}

// block-local exclusive scan of cnt -> rp (local), block totals -> part
__global__ void k_scan1(const int* __restrict__ cnt, int* __restrict__ rp,
                        int* __restrict__ part, int N) {
    __shared__ int s[256];
    int i = blockIdx.x * 256 + threadIdx.x;
    int v = (i < N) ? cnt[i] : 0;
    s[threadIdx.x] = v;
    int x = v;
    for (int off = 1; off < 256; off <<= 1) {
        __syncthreads();
        int add = (threadIdx.x >= off) ? s[threadIdx.x - off] : 0;
        __syncthreads();
        x += add;
        s[threadIdx.x] = x;
    }
    if (i < N) rp[i] = x - v;                     // exclusive
    __syncthreads();
    if (threadIdx.x == 255) part[blockIdx.x] = s[255];
}

// single-block exclusive scan of part[0..B)
__global__ void k_scan2(int* __restrict__ part, int B) {
    __shared__ int s[512];
    int t = threadIdx.x;
    int v = (t < B) ? part[t] : 0;
    s[t] = v;
    int x = v;
    for (int off = 1; off < 512; off <<= 1) {
        __syncthreads();
        int add = (t >= off) ? s[t - off] : 0;
        __syncthreads();
        x += add;
        s[t] = x;
    }
    if (t < B) part[t] = x - v;
}

__global__ void k_scan3(int* __restrict__ rp, const int* __restrict__ part,
                        int* __restrict__ next, int N, int E) {
    int i = blockIdx.x * 256 + threadIdx.x;
    if (i < N) {
        int v = rp[i] + part[i >> 8];
        rp[i] = v;
        next[i] = v;                              // fill cursor
    }
    if (i == 0) rp[N] = E;
}

__global__ void k_build(const int* __restrict__ src, const int* __restrict__ dst,
                        int* __restrict__ next, int* __restrict__ col, int E) {
    int e = blockIdx.x * blockDim.x + threadIdx.x;
    if (e < E) {
        int pos = atomicAdd(&next[dst[e]], 1);
        col[pos] = src[e];
    }
}

// ---------------- tiny folded tables (fp32 inputs) ----------------
__global__ void k_small(const float* __restrict__ W2,
                        const float* __restrict__ emb0, const float* __restrict__ emb1,
                        const float* __restrict__ fcW1, const float* __restrict__ fcb1,
                        const float* __restrict__ fcW2, const float* __restrict__ fcb2,
                        float* __restrict__ U, float* __restrict__ E0t,
                        float* __restrict__ E1t, float* __restrict__ C) {
    int t = threadIdx.x; // 64 threads
    for (int c = 0; c < 2; ++c) {
        float s = 0.f;
        for (int j = 0; j < 64; ++j) s += W2[t * 64 + j] * fcW1[j * 2 + c];
        U[t * 2 + c] = s;                         // U = W2 @ fcW1[0:64,:]
    }
    if (t < 20) {
        for (int c = 0; c < 2; ++c) {
            float s0 = 0.f, s1 = 0.f;
            for (int k = 0; k < 32; ++k) {
                s0 += emb0[t * 32 + k] * fcW1[(66 + k) * 2 + c];
                s1 += emb1[t * 32 + k] * fcW1[(98 + k) * 2 + c];
            }
            E0t[t * 2 + c] = s0;
            E1t[t * 2 + c] = s1;
        }
    }
    if (t == 0) {
        C[0] = fcb1[0];                           // b2 cancels in h2[s]-h2[d]!
        C[1] = fcb1[1];
        C[2] = fcW1[64 * 2 + 0]; C[3] = fcW1[64 * 2 + 1];
        C[4] = fcW1[65 * 2 + 0]; C[5] = fcW1[65 * 2 + 1];
        C[6] = fcW2[0]; C[7] = fcW2[1];
        C[8] = fcW2[2]; C[9] = fcW2[3];
        C[10] = fcb2[0]; C[11] = fcb2[1];
    }
}

// ---------------- xW = x @ W1 (fp32 in, bf16 out) ----------------
__global__ __launch_bounds__(256) void k_gemm1(const float* __restrict__ x,
                                               const float* __restrict__ W1,
                                               bf16* __restrict__ xW, int N) {
    __shared__ float Ws[64 * 64];
    int tid = threadIdx.x;
    for (int i = tid; i < 4096; i += 256) Ws[i] = W1[i];
    __syncthreads();
    int lane = tid & 63;
    int wave = tid >> 6;
    int n0 = blockIdx.x * 16 + wave * 4;
    float xv0 = (n0 + 0 < N) ? x[(size_t)(n0 + 0) * 64 + lane] : 0.f;
    float xv1 = (n0 + 1 < N) ? x[(size_t)(n0 + 1) * 64 + lane] : 0.f;
    float xv2 = (n0 + 2 < N) ? x[(size_t)(n0 + 2) * 64 + lane] : 0.f;
    float xv3 = (n0 + 3 < N) ? x[(size_t)(n0 + 3) * 64 + lane] : 0.f;
    float a0 = 0.f, a1 = 0.f, a2 = 0.f, a3 = 0.f;
#pragma unroll 8
    for (int i = 0; i < 64; ++i) {
        float w = Ws[i * 64 + lane];
        a0 = fmaf(__shfl(xv0, i), w, a0);
        a1 = fmaf(__shfl(xv1, i), w, a1);
        a2 = fmaf(__shfl(xv2, i), w, a2);
        a3 = fmaf(__shfl(xv3, i), w, a3);
    }
    if (n0 + 0 < N) xW[(size_t)(n0 + 0) * 64 + lane] = __float2bfloat16(a0);
    if (n0 + 1 < N) xW[(size_t)(n0 + 1) * 64 + lane] = __float2bfloat16(a1);
    if (n0 + 2 < N) xW[(size_t)(n0 + 2) * 64 + lane] = __float2bfloat16(a2);
    if (n0 + 3 < N) xW[(size_t)(n0 + 3) * 64 + lane] = __float2bfloat16(a3);
}

// ---------------- conv1 gather + relu + 64->2 projection ----------------
__global__ __launch_bounds__(256) void k_gather1(
        const bf16* __restrict__ xW, const float* __restrict__ dinv,
        const int* __restrict__ rp, const int* __restrict__ col,
        const float* __restrict__ b1, const float* __restrict__ U,
        float* __restrict__ Q, float* __restrict__ P, int N) {
    int wid = (blockIdx.x * 256 + threadIdx.x) >> 6;
    int o = threadIdx.x & 63;
    if (wid >= N) return;
    float di = dinv[wid];
    float acc = di * di * __bfloat162float(xW[(size_t)wid * 64 + o]); // self-loop
    int beg = rp[wid], end = rp[wid + 1];
    for (int j = beg; j < end; ++j) {
        int m = col[j];                                    // wave-uniform broadcast
        float w = di * dinv[m];
        acc = fmaf(w, __bfloat162float(xW[(size_t)m * 64 + o]), acc);
    }
    float h = fmaxf(acc + b1[o], 0.f);
    float q0 = h * U[o * 2 + 0];
    float q1 = h * U[o * 2 + 1];
#pragma unroll
    for (int mm = 32; mm; mm >>= 1) {
        q0 += __shfl_xor(q0, mm);
        q1 += __shfl_xor(q1, mm);
    }
    if (o == 0) {
        float d2 = di * di;
        Q[2 * wid + 0] = q0;      Q[2 * wid + 1] = q1;
        P[2 * wid + 0] = d2 * q0; P[2 * wid + 1] = d2 * q1;  // conv2 self-loop
    }
}

// ---------------- conv2 scalar gather (no atomics) ----------------
__global__ void k_gather2(const float* __restrict__ dinv, const int* __restrict__ rp,
                          const int* __restrict__ col, const float* __restrict__ Q,
                          float* __restrict__ P, int N) {
    int n = blockIdx.x * blockDim.x + threadIdx.x;
    if (n >= N) return;
    float di = dinv[n];
    float p0 = P[2 * n + 0], p1 = P[2 * n + 1];
    int beg = rp[n], end = rp[n + 1];
    for (int j = beg; j < end; ++j) {
        int m = col[j];
        float w = di * dinv[m];
        float2 q = ((const float2*)Q)[m];
        p0 = fmaf(w, q.x, p0);
        p1 = fmaf(w, q.y, p1);
    }
    P[2 * n + 0] = p0;
    P[2 * n + 1] = p1;
}

// ---------------- per-edge epilogue -> fp32 out ----------------
__global__ void k_edge(const int* __restrict__ src, const int* __restrict__ dst,
                       const int* __restrict__ attr, const float* __restrict__ P,
                       const float* __restrict__ E0t, const float* __restrict__ E1t,
                       const float* __restrict__ C, float* __restrict__ out, int E) {
    int e = blockIdx.x * blockDim.x + threadIdx.x;
    if (e >= E) return;
    int s = src[e], d = dst[e];
    float a0 = (float)attr[e];
    float a1 = (float)attr[E + e];
    int i2 = attr[2 * E + e], i3 = attr[3 * E + e];
    const float2* P2 = (const float2*)P;
    float2 ps = P2[s], pd = P2[d];
    float z0 = ps.x - pd.x + a0 * C[2] + a1 * C[4] + E0t[i2 * 2 + 0] + E1t[i3 * 2 + 0] + C[0];
    float z1 = ps.y - pd.y + a0 * C[3] + a1 * C[5] + E0t[i2 * 2 + 1] + E1t[i3 * 2 + 1] + C[1];
    float r0 = fmaxf(z0, 0.f), r1 = fmaxf(z1, 0.f);
    float o0 = r0 * C[6] + r1 * C[8] + C[10];
    float o1 = r0 * C[7] + r1 * C[9] + C[11];
    float m = fmaxf(o0, o1);
    float lse = m + logf(expf(o0 - m) + expf(o1 - m));
    float2 res;
    res.x = o0 - lse;
    res.y = o1 - lse;
    ((float2*)out)[e] = res;
}

extern "C" void kernel_launch(void* const* d_in, const int* in_sizes, int n_in,
                              void* d_out, int out_size, void* d_ws, size_t ws_size,
                              hipStream_t stream) {
    const float* x    = (const float*)d_in[0];
    const int*   ei   = (const int*)d_in[1];
    const int*   ea   = (const int*)d_in[2];
    const float* W1   = (const float*)d_in[3];
    const float* b1   = (const float*)d_in[4];
    const float* W2   = (const float*)d_in[5];
    const float* emb0 = (const float*)d_in[7];
    const float* emb1 = (const float*)d_in[8];
    const float* fcW1 = (const float*)d_in[9];
    const float* fcb1 = (const float*)d_in[10];
    const float* fcW2 = (const float*)d_in[11];
    const float* fcb2 = (const float*)d_in[12];

    const int N = in_sizes[0] / 64;
    const int E = in_sizes[1] / 2;
    const int* src = ei;
    const int* dst = ei + E;
    const int B1 = (N + 255) / 256;               // scan blocks (<=512)

    // ws layout (4-byte words), total ~15.6 MB:
    char* wsb = (char*)d_ws;
    float* dinv = (float*)wsb;                             // N
    int*   rp   = (int*)(wsb + (size_t)4 * 100352);        // N+1
    int*   next = (int*)(wsb + (size_t)4 * 200704);        // N (hist, then cursor)
    int*   part = (int*)(wsb + (size_t)4 * 300800);        // 512
    float* U    = (float*)(wsb + (size_t)4 * 301312);      // 128
    float* E0t  = U + 128;                                 // 40
    float* E1t  = E0t + 40;                                // 40
    float* C    = E1t + 40;                                // 12
    float* Q    = (float*)(wsb + (size_t)4 * 301568);      // 2N
    float* P    = (float*)(wsb + (size_t)4 * 501760);      // 2N
    bf16*  xW   = (bf16*)(wsb + (size_t)4 * 702464);       // N*64 bf16 (12.8 MB)
    int*   col  = (int*)d_out;                             // E ints, overwritten by k_edge

    k_small<<<1, 64, 0, stream>>>(W2, emb0, emb1, fcW1, fcb1, fcW2, fcb2,
                                  U, E0t, E1t, C);
    k_zero<<<(N + 255) / 256, 256, 0, stream>>>(next, N);
    k_hist<<<(E + 255) / 256, 256, 0, stream>>>(dst, next, E);
    k_dinvk<<<(N + 255) / 256, 256, 0, stream>>>(next, dinv, N);
    k_scan1<<<B1, 256, 0, stream>>>(next, rp, part, N);
    k_scan2<<<1, 512, 0, stream>>>(part, B1);
    k_scan3<<<B1, 256, 0, stream>>>(rp, part, next, N, E);
    k_build<<<(E + 255) / 256, 256, 0, stream>>>(src, dst, next, col, E);
    k_gemm1<<<(N + 15) / 16, 256, 0, stream>>>(x, W1, xW, N);
    k_gather1<<<((size_t)N * 64 + 255) / 256, 256, 0, stream>>>(xW, dinv, rp, col, b1, U, Q, P, N);
    k_gather2<<<(N + 255) / 256, 256, 0, stream>>>(dinv, rp, col, Q, P, N);
    k_edge<<<(E + 255) / 256, 256, 0, stream>>>(src, dst, ea, P, E0t, E1t, C,
                                                (float*)d_out, E);
}

// Round 5
// 429.137 us; speedup vs baseline: 1.4242x; 1.4242x over previous
//
#include <hip/hip_runtime.h>
#include <hip/hip_bf16.h>
#include <math.h>

// ---------------------------------------------------------------------------
// GCNWithEdge, algebraically folded + CSR gather. FP32 in/out, int32 indices.
//   h1 = relu(Anorm @ (x@W1) + b1)
//   Q[n][c]  = h1[n] . U[:,c],   U = W2 @ fcW1[0:64,:]
//   P[n][c]  = sum_{e:dst=n} norm*Q[src][c] + dinv^2*Q[n][c]
//   z[e][c]  = P[s]-P[d] + a0*fcW1[64,c] + a1*fcW1[65,c] + E0t[a2] + E1t[a3] + fcb1
//   out = log_softmax( relu(z) @ fcW2 + fcb2 )
// R4 counters: gather1 latency-bound (5.7% HBM, VALU 17.6%) -> MLP-8 unroll +
// lane-parallel col staging. gemm1 shuffle-bound -> LDS-tiled 4x4 register GEMM.
// ---------------------------------------------------------------------------

typedef __hip_bfloat16 bf16;

// ---------------- degree / CSR build ----------------
__global__ void k_zero(int* __restrict__ a, int N) {
    int i = blockIdx.x * blockDim.x + threadIdx.x;
    if (i < N) a[i] = 0;
}

__global__ void k_hist(const int* __restrict__ dst, int* __restrict__ cnt, int E) {
    int e = blockIdx.x * blockDim.x + threadIdx.x;
    if (e < E) atomicAdd(&cnt[dst[e]], 1);
}

// block-local exclusive scan of cnt -> rp, block totals -> part, dinv fused
__global__ void k_scan1(const int* __restrict__ cnt, int* __restrict__ rp,
                        int* __restrict__ part, float* __restrict__ dinv, int N) {
    __shared__ int s[256];
    int i = blockIdx.x * 256 + threadIdx.x;
    int v = (i < N) ? cnt[i] : 0;
    if (i < N) dinv[i] = rsqrtf((float)v + 1.0f);  // +1 self-loop
    s[threadIdx.x] = v;
    int x = v;
    for (int off = 1; off < 256; off <<= 1) {
        __syncthreads();
        int add = (threadIdx.x >= off) ? s[threadIdx.x - off] : 0;
        __syncthreads();
        x += add;
        s[threadIdx.x] = x;
    }
    if (i < N) rp[i] = x - v;                     // exclusive
    __syncthreads();
    if (threadIdx.x == 255) part[blockIdx.x] = s[255];
}

__global__ void k_scan2(int* __restrict__ part, int B) {
    __shared__ int s[512];
    int t = threadIdx.x;
    int v = (t < B) ? part[t] : 0;
    s[t] = v;
    int x = v;
    for (int off = 1; off < 512; off <<= 1) {
        __syncthreads();
        int add = (t >= off) ? s[t - off] : 0;
        __syncthreads();
        x += add;
        s[t] = x;
    }
    if (t < B) part[t] = x - v;
}

__global__ void k_scan3(int* __restrict__ rp, const int* __restrict__ part,
                        int* __restrict__ next, int N, int E) {
    int i = blockIdx.x * 256 + threadIdx.x;
    if (i < N) {
        int v = rp[i] + part[i >> 8];
        rp[i] = v;
        next[i] = v;
    }
    if (i == 0) rp[N] = E;
}

__global__ void k_build(const int* __restrict__ src, const int* __restrict__ dst,
                        int* __restrict__ next, int* __restrict__ col, int E) {
    int e = blockIdx.x * blockDim.x + threadIdx.x;
    if (e < E) {
        int pos = atomicAdd(&next[dst[e]], 1);
        col[pos] = src[e];
    }
}

// ---------------- tiny folded tables ----------------
__global__ void k_small(const float* __restrict__ W2,
                        const float* __restrict__ emb0, const float* __restrict__ emb1,
                        const float* __restrict__ fcW1, const float* __restrict__ fcb1,
                        const float* __restrict__ fcW2, const float* __restrict__ fcb2,
                        float* __restrict__ U, float* __restrict__ E0t,
                        float* __restrict__ E1t, float* __restrict__ C) {
    int t = threadIdx.x; // 64 threads
    for (int c = 0; c < 2; ++c) {
        float s = 0.f;
        for (int j = 0; j < 64; ++j) s += W2[t * 64 + j] * fcW1[j * 2 + c];
        U[t * 2 + c] = s;
    }
    if (t < 20) {
        for (int c = 0; c < 2; ++c) {
            float s0 = 0.f, s1 = 0.f;
            for (int k = 0; k < 32; ++k) {
                s0 += emb0[t * 32 + k] * fcW1[(66 + k) * 2 + c];
                s1 += emb1[t * 32 + k] * fcW1[(98 + k) * 2 + c];
            }
            E0t[t * 2 + c] = s0;
            E1t[t * 2 + c] = s1;
        }
    }
    if (t == 0) {
        C[0] = fcb1[0];                           // b2 cancels in h2[s]-h2[d]
        C[1] = fcb1[1];
        C[2] = fcW1[64 * 2 + 0]; C[3] = fcW1[64 * 2 + 1];
        C[4] = fcW1[65 * 2 + 0]; C[5] = fcW1[65 * 2 + 1];
        C[6] = fcW2[0]; C[7] = fcW2[1];
        C[8] = fcW2[2]; C[9] = fcW2[3];
        C[10] = fcb2[0]; C[11] = fcb2[1];
    }
}

// ---------------- xW = x @ W1, LDS-tiled 4x4 register blocking ----------------
__global__ __launch_bounds__(256) void k_gemm1(const float* __restrict__ x,
                                               const float* __restrict__ W1,
                                               bf16* __restrict__ xW, int N) {
    __shared__ __align__(16) float xs[64][68];   // transposed x tile, padded
    __shared__ __align__(16) float Ws[64][64];
    int tid = threadIdx.x;
    int n0 = blockIdx.x * 64;
    for (int i = tid; i < 4096; i += 256) Ws[i >> 6][i & 63] = W1[i];
    for (int i = tid; i < 4096; i += 256) {
        int node = i >> 6, k = i & 63;
        float v = (n0 + node < N) ? x[(size_t)(n0 + node) * 64 + k] : 0.f;
        xs[k][node] = v;
    }
    __syncthreads();
    int tr = tid >> 4;        // node group (0..15)
    int tc = tid & 15;        // out group  (0..15)
    float acc[4][4] = {};
#pragma unroll 8
    for (int k = 0; k < 64; ++k) {
        float4 xv = *(const float4*)&xs[k][tr * 4];
        float4 wv = *(const float4*)&Ws[k][tc * 4];
        acc[0][0] = fmaf(xv.x, wv.x, acc[0][0]);
        acc[0][1] = fmaf(xv.x, wv.y, acc[0][1]);
        acc[0][2] = fmaf(xv.x, wv.z, acc[0][2]);
        acc[0][3] = fmaf(xv.x, wv.w, acc[0][3]);
        acc[1][0] = fmaf(xv.y, wv.x, acc[1][0]);
        acc[1][1] = fmaf(xv.y, wv.y, acc[1][1]);
        acc[1][2] = fmaf(xv.y, wv.z, acc[1][2]);
        acc[1][3] = fmaf(xv.y, wv.w, acc[1][3]);
        acc[2][0] = fmaf(xv.z, wv.x, acc[2][0]);
        acc[2][1] = fmaf(xv.z, wv.y, acc[2][1]);
        acc[2][2] = fmaf(xv.z, wv.z, acc[2][2]);
        acc[2][3] = fmaf(xv.z, wv.w, acc[2][3]);
        acc[3][0] = fmaf(xv.w, wv.x, acc[3][0]);
        acc[3][1] = fmaf(xv.w, wv.y, acc[3][1]);
        acc[3][2] = fmaf(xv.w, wv.z, acc[3][2]);
        acc[3][3] = fmaf(xv.w, wv.w, acc[3][3]);
    }
#pragma unroll
    for (int i = 0; i < 4; ++i) {
        int node = n0 + tr * 4 + i;
        if (node < N) {
            __hip_bfloat162 p0, p1;
            p0.x = __float2bfloat16(acc[i][0]);
            p0.y = __float2bfloat16(acc[i][1]);
            p1.x = __float2bfloat16(acc[i][2]);
            p1.y = __float2bfloat16(acc[i][3]);
            __hip_bfloat162* dst2 = (__hip_bfloat162*)&xW[(size_t)node * 64 + tc * 4];
            dst2[0] = p0;
            dst2[1] = p1;
        }
    }
}

// ---------------- conv1 gather (MLP-8) + relu + 64->2 projection ----------------
__global__ __launch_bounds__(256) void k_gather1(
        const bf16* __restrict__ xW, const float* __restrict__ dinv,
        const int* __restrict__ rp, const int* __restrict__ col,
        const float* __restrict__ b1, const float* __restrict__ U,
        float* __restrict__ Q, float* __restrict__ P, int N, int E) {
    int wid = (blockIdx.x * 256 + threadIdx.x) >> 6;
    int o = threadIdx.x & 63;
    if (wid >= N) return;
    float di = dinv[wid];
    float acc = di * __bfloat162float(xW[(size_t)wid * 64 + o]); // self (x di later)
    int beg = rp[wid], end = rp[wid + 1];
    for (int base = beg; base < end; base += 64) {
        int nn = min(64, end - base);
        // stage up to 64 neighbor ids: one coalesced load, broadcast via shfl
        int colv = col[min(base + o, E - 1)];
        int jj = 0;
        for (; jj + 8 <= nn; jj += 8) {
            int m0 = __shfl(colv, jj + 0);
            int m1 = __shfl(colv, jj + 1);
            int m2 = __shfl(colv, jj + 2);
            int m3 = __shfl(colv, jj + 3);
            int m4 = __shfl(colv, jj + 4);
            int m5 = __shfl(colv, jj + 5);
            int m6 = __shfl(colv, jj + 6);
            int m7 = __shfl(colv, jj + 7);
            float w0 = dinv[m0], w1 = dinv[m1], w2 = dinv[m2], w3 = dinv[m3];
            float w4 = dinv[m4], w5 = dinv[m5], w6 = dinv[m6], w7 = dinv[m7];
            float v0 = __bfloat162float(xW[(size_t)m0 * 64 + o]);
            float v1 = __bfloat162float(xW[(size_t)m1 * 64 + o]);
            float v2 = __bfloat162float(xW[(size_t)m2 * 64 + o]);
            float v3 = __bfloat162float(xW[(size_t)m3 * 64 + o]);
            float v4 = __bfloat162float(xW[(size_t)m4 * 64 + o]);
            float v5 = __bfloat162float(xW[(size_t)m5 * 64 + o]);
            float v6 = __bfloat162float(xW[(size_t)m6 * 64 + o]);
            float v7 = __bfloat162float(xW[(size_t)m7 * 64 + o]);
            acc = fmaf(w0, v0, acc);
            acc = fmaf(w1, v1, acc);
            acc = fmaf(w2, v2, acc);
            acc = fmaf(w3, v3, acc);
            acc = fmaf(w4, v4, acc);
            acc = fmaf(w5, v5, acc);
            acc = fmaf(w6, v6, acc);
            acc = fmaf(w7, v7, acc);
        }
        for (; jj < nn; ++jj) {
            int m = __shfl(colv, jj);
            acc = fmaf(dinv[m], __bfloat162float(xW[(size_t)m * 64 + o]), acc);
        }
    }
    acc *= di;
    float h = fmaxf(acc + b1[o], 0.f);
    float q0 = h * U[o * 2 + 0];
    float q1 = h * U[o * 2 + 1];
#pragma unroll
    for (int mm = 32; mm; mm >>= 1) {
        q0 += __shfl_xor(q0, mm);
        q1 += __shfl_xor(q1, mm);
    }
    if (o == 0) {
        float d2 = di * di;
        Q[2 * wid + 0] = q0;      Q[2 * wid + 1] = q1;
        P[2 * wid + 0] = d2 * q0; P[2 * wid + 1] = d2 * q1;  // conv2 self-loop
    }
}

// ---------------- conv2 scalar gather ----------------
__global__ void k_gather2(const float* __restrict__ dinv, const int* __restrict__ rp,
                          const int* __restrict__ col, const float* __restrict__ Q,
                          float* __restrict__ P, int N) {
    int n = blockIdx.x * blockDim.x + threadIdx.x;
    if (n >= N) return;
    float di = dinv[n];
    float p0 = P[2 * n + 0], p1 = P[2 * n + 1];
    int beg = rp[n], end = rp[n + 1];
    for (int j = beg; j < end; ++j) {
        int m = col[j];
        float w = di * dinv[m];
        float2 q = ((const float2*)Q)[m];
        p0 = fmaf(w, q.x, p0);
        p1 = fmaf(w, q.y, p1);
    }
    P[2 * n + 0] = p0;
    P[2 * n + 1] = p1;
}

// ---------------- per-edge epilogue -> fp32 out ----------------
__global__ void k_edge(const int* __restrict__ src, const int* __restrict__ dst,
                       const int* __restrict__ attr, const float* __restrict__ P,
                       const float* __restrict__ E0t, const float* __restrict__ E1t,
                       const float* __restrict__ C, float* __restrict__ out, int E) {
    int e = blockIdx.x * blockDim.x + threadIdx.x;
    if (e >= E) return;
    int s = src[e], d = dst[e];
    float a0 = (float)attr[e];
    float a1 = (float)attr[E + e];
    int i2 = attr[2 * E + e], i3 = attr[3 * E + e];
    const float2* P2 = (const float2*)P;
    float2 ps = P2[s], pd = P2[d];
    float z0 = ps.x - pd.x + a0 * C[2] + a1 * C[4] + E0t[i2 * 2 + 0] + E1t[i3 * 2 + 0] + C[0];
    float z1 = ps.y - pd.y + a0 * C[3] + a1 * C[5] + E0t[i2 * 2 + 1] + E1t[i3 * 2 + 1] + C[1];
    float r0 = fmaxf(z0, 0.f), r1 = fmaxf(z1, 0.f);
    float o0 = r0 * C[6] + r1 * C[8] + C[10];
    float o1 = r0 * C[7] + r1 * C[9] + C[11];
    float m = fmaxf(o0, o1);
    float lse = m + logf(expf(o0 - m) + expf(o1 - m));
    float2 res;
    res.x = o0 - lse;
    res.y = o1 - lse;
    ((float2*)out)[e] = res;
}

extern "C" void kernel_launch(void* const* d_in, const int* in_sizes, int n_in,
                              void* d_out, int out_size, void* d_ws, size_t ws_size,
                              hipStream_t stream) {
    const float* x    = (const float*)d_in[0];
    const int*   ei   = (const int*)d_in[1];
    const int*   ea   = (const int*)d_in[2];
    const float* W1   = (const float*)d_in[3];
    const float* b1   = (const float*)d_in[4];
    const float* W2   = (const float*)d_in[5];
    const float* emb0 = (const float*)d_in[7];
    const float* emb1 = (const float*)d_in[8];
    const float* fcW1 = (const float*)d_in[9];
    const float* fcb1 = (const float*)d_in[10];
    const float* fcW2 = (const float*)d_in[11];
    const float* fcb2 = (const float*)d_in[12];

    const int N = in_sizes[0] / 64;
    const int E = in_sizes[1] / 2;
    const int* src = ei;
    const int* dst = ei + E;
    const int B1 = (N + 255) / 256;               // scan blocks (<=512)

    // ws layout (4-byte words), total ~15.6 MB:
    char* wsb = (char*)d_ws;
    float* dinv = (float*)wsb;                             // N
    int*   rp   = (int*)(wsb + (size_t)4 * 100352);        // N+1
    int*   next = (int*)(wsb + (size_t)4 * 200704);        // N (hist, then cursor)
    int*   part = (int*)(wsb + (size_t)4 * 300800);        // 512
    float* U    = (float*)(wsb + (size_t)4 * 301312);      // 128
    float* E0t  = U + 128;                                 // 40
    float* E1t  = E0t + 40;                                // 40
    float* C    = E1t + 40;                                // 12
    float* Q    = (float*)(wsb + (size_t)4 * 301568);      // 2N
    float* P    = (float*)(wsb + (size_t)4 * 501760);      // 2N
    bf16*  xW   = (bf16*)(wsb + (size_t)4 * 702464);       // N*64 bf16 (12.8 MB)
    int*   col  = (int*)d_out;                             // E ints, overwritten by k_edge

    k_small<<<1, 64, 0, stream>>>(W2, emb0, emb1, fcW1, fcb1, fcW2, fcb2,
                                  U, E0t, E1t, C);
    k_zero<<<(N + 255) / 256, 256, 0, stream>>>(next, N);
    k_hist<<<(E + 255) / 256, 256, 0, stream>>>(dst, next, E);
    k_scan1<<<B1, 256, 0, stream>>>(next, rp, part, dinv, N);
    k_scan2<<<1, 512, 0, stream>>>(part, B1);
    k_scan3<<<B1, 256, 0, stream>>>(rp, part, next, N, E);
    k_build<<<(E + 255) / 256, 256, 0, stream>>>(src, dst, next, col, E);
    k_gemm1<<<(N + 63) / 64, 256, 0, stream>>>(x, W1, xW, N);
    k_gather1<<<((size_t)N * 64 + 255) / 256, 256, 0, stream>>>(xW, dinv, rp, col, b1, U, Q, P, N, E);
    k_gather2<<<(N + 255) / 256, 256, 0, stream>>>(dinv, rp, col, Q, P, N);
    k_edge<<<(E + 255) / 256, 256, 0, stream>>>(src, dst, ea, P, E0t, E1t, C,
                                                (float*)d_out, E);
}

// Round 6
// 297.593 us; speedup vs baseline: 2.0537x; 1.4420x over previous
//
#include <hip/hip_runtime.h>
#include <hip/hip_bf16.h>
#include <math.h>

// ---------------------------------------------------------------------------
// GCNWithEdge, algebraically folded + bucketed CSR gather. FP32 in/out.
//   h1 = relu(Anorm @ (x@W1) + b1)
//   Q[n][c]  = h1[n] . U[:,c],   U = W2 @ fcW1[0:64,:]
//   P[n][c]  = sum_{e:dst=n} norm*Q[src][c] + dinv^2*Q[n][c]
//   z[e][c]  = P[s]-P[d] + a0*fcW1[64,c] + a1*fcW1[65,c] + E0t[a2]+E1t[a3]+fcb1
//   out = log_softmax( relu(z) @ fcW2 + fcb2 )
// R5: k_build wrote 105 MB (4B-in-64B line scatter). Replaced by 2-level
// bucket sort: kA (block-bucket hist) -> scan -> kB (coalesced pair placement,
// 4B packed (local<<17)|src) -> kC (per-bucket CSR: LDS count/scan, dinv, col
// writes confined to one CU's 16KB window). k_hist/k_zero eliminated.
// ---------------------------------------------------------------------------

typedef __hip_bfloat16 bf16;
#define NBLK 256          // blocks for kA/kB (must match between them)

// ---- kA: per-(bucket,block) histogram ----
__global__ __launch_bounds__(256) void kA(const int* __restrict__ dst,
                                          int* __restrict__ cntm,
                                          int E, int chunk, int NB) {
    __shared__ int h[512];
    int blk = blockIdx.x;
    for (int i = threadIdx.x; i < NB; i += 256) h[i] = 0;
    __syncthreads();
    int lo = blk * chunk, hi = min(E, lo + chunk);
    for (int e = lo + threadIdx.x; e < hi; e += 256)
        atomicAdd(&h[dst[e] >> 8], 1);
    __syncthreads();
    for (int i = threadIdx.x; i < NB; i += 256)
        cntm[(size_t)i * NBLK + blk] = h[i];
}

// ---- in-place exclusive scan of cntm (3 kernels, M = NB*NBLK) ----
__global__ void k_mscan1(int* __restrict__ a, int* __restrict__ part, int M) {
    __shared__ int s[256];
    int i = blockIdx.x * 256 + threadIdx.x;
    int v = (i < M) ? a[i] : 0;
    s[threadIdx.x] = v;
    int x = v;
    for (int off = 1; off < 256; off <<= 1) {
        __syncthreads();
        int add = (threadIdx.x >= off) ? s[threadIdx.x - off] : 0;
        __syncthreads();
        x += add;
        s[threadIdx.x] = x;
    }
    if (i < M) a[i] = x - v;
    __syncthreads();
    if (threadIdx.x == 255) part[blockIdx.x] = s[255];
}

__global__ void k_scan2(int* __restrict__ part, int B) {
    __shared__ int s[512];
    int t = threadIdx.x;
    int v = (t < B) ? part[t] : 0;
    s[t] = v;
    int x = v;
    for (int off = 1; off < 512; off <<= 1) {
        __syncthreads();
        int add = (t >= off) ? s[t - off] : 0;
        __syncthreads();
        x += add;
        s[t] = x;
    }
    if (t < B) part[t] = x - v;
}

__global__ void k_mscan3(int* __restrict__ a, const int* __restrict__ part, int M) {
    int i = blockIdx.x * 256 + threadIdx.x;
    if (i < M) a[i] += part[blockIdx.x];
}

// ---- kB: place packed pairs into bucket-major array (block-private ranges) ----
__global__ __launch_bounds__(256) void kB(const int* __restrict__ src,
                                          const int* __restrict__ dst,
                                          const int* __restrict__ cntm,
                                          int* __restrict__ pairs,
                                          int E, int chunk, int NB) {
    __shared__ int off[512];
    int blk = blockIdx.x;
    for (int i = threadIdx.x; i < NB; i += 256)
        off[i] = cntm[(size_t)i * NBLK + blk];
    __syncthreads();
    int lo = blk * chunk, hi = min(E, lo + chunk);
    for (int e = lo + threadIdx.x; e < hi; e += 256) {
        int d = dst[e];
        int pos = atomicAdd(&off[d >> 8], 1);
        pairs[pos] = ((d & 255) << 17) | src[e];
    }
}

// ---- kC: per-bucket CSR finalize: dinv, rp, col (all local/coalesced) ----
__global__ __launch_bounds__(256) void kC(const int* __restrict__ cntm,
                                          const int* __restrict__ pairs,
                                          int* __restrict__ col, int* __restrict__ rp,
                                          float* __restrict__ dinv,
                                          int N, int E, int NB) {
    __shared__ int cnt[256];
    __shared__ int s[256];
    int b = blockIdx.x, t = threadIdx.x;
    int n0 = b << 8;
    int nn = min(256, N - n0);
    int base = cntm[(size_t)b * NBLK];
    int end  = (b == NB - 1) ? E : cntm[(size_t)(b + 1) * NBLK];
    cnt[t] = 0;
    __syncthreads();
    for (int j = base + t; j < end; j += 256)
        atomicAdd(&cnt[pairs[j] >> 17], 1);
    __syncthreads();
    int v = cnt[t];
    if (t < nn) dinv[n0 + t] = rsqrtf((float)v + 1.0f);   // +1 self-loop
    s[t] = v;
    int x = v;
    for (int off = 1; off < 256; off <<= 1) {
        __syncthreads();
        int add = (t >= off) ? s[t - off] : 0;
        __syncthreads();
        x += add;
        s[t] = x;
    }
    __syncthreads();
    int excl = x - v;
    if (t < nn) rp[n0 + t] = base + excl;
    cnt[t] = base + excl;                                 // cursor
    __syncthreads();
    for (int j = base + t; j < end; j += 256) {
        int v2 = pairs[j];
        int pos = atomicAdd(&cnt[v2 >> 17], 1);
        col[pos] = v2 & 0x1FFFF;
    }
    if (b == NB - 1 && t == 0) rp[N] = E;
}

// ---------------- tiny folded tables ----------------
__global__ void k_small(const float* __restrict__ W2,
                        const float* __restrict__ emb0, const float* __restrict__ emb1,
                        const float* __restrict__ fcW1, const float* __restrict__ fcb1,
                        const float* __restrict__ fcW2, const float* __restrict__ fcb2,
                        float* __restrict__ U, float* __restrict__ E0t,
                        float* __restrict__ E1t, float* __restrict__ C) {
    int t = threadIdx.x; // 64 threads
    for (int c = 0; c < 2; ++c) {
        float s = 0.f;
        for (int j = 0; j < 64; ++j) s += W2[t * 64 + j] * fcW1[j * 2 + c];
        U[t * 2 + c] = s;
    }
    if (t < 20) {
        for (int c = 0; c < 2; ++c) {
            float s0 = 0.f, s1 = 0.f;
            for (int k = 0; k < 32; ++k) {
                s0 += emb0[t * 32 + k] * fcW1[(66 + k) * 2 + c];
                s1 += emb1[t * 32 + k] * fcW1[(98 + k) * 2 + c];
            }
            E0t[t * 2 + c] = s0;
            E1t[t * 2 + c] = s1;
        }
    }
    if (t == 0) {
        C[0] = fcb1[0];                           // b2 cancels in h2[s]-h2[d]
        C[1] = fcb1[1];
        C[2] = fcW1[64 * 2 + 0]; C[3] = fcW1[64 * 2 + 1];
        C[4] = fcW1[65 * 2 + 0]; C[5] = fcW1[65 * 2 + 1];
        C[6] = fcW2[0]; C[7] = fcW2[1];
        C[8] = fcW2[2]; C[9] = fcW2[3];
        C[10] = fcb2[0]; C[11] = fcb2[1];
    }
}

// ---------------- xW = x @ W1, LDS-tiled 4x4 register blocking ----------------
__global__ __launch_bounds__(256) void k_gemm1(const float* __restrict__ x,
                                               const float* __restrict__ W1,
                                               bf16* __restrict__ xW, int N) {
    __shared__ __align__(16) float xs[64][68];
    __shared__ __align__(16) float Ws[64][64];
    int tid = threadIdx.x;
    int n0 = blockIdx.x * 64;
    for (int i = tid; i < 4096; i += 256) Ws[i >> 6][i & 63] = W1[i];
    for (int i = tid; i < 4096; i += 256) {
        int node = i >> 6, k = i & 63;
        float v = (n0 + node < N) ? x[(size_t)(n0 + node) * 64 + k] : 0.f;
        xs[k][node] = v;
    }
    __syncthreads();
    int tr = tid >> 4;
    int tc = tid & 15;
    float acc[4][4] = {};
#pragma unroll 8
    for (int k = 0; k < 64; ++k) {
        float4 xv = *(const float4*)&xs[k][tr * 4];
        float4 wv = *(const float4*)&Ws[k][tc * 4];
        acc[0][0] = fmaf(xv.x, wv.x, acc[0][0]);
        acc[0][1] = fmaf(xv.x, wv.y, acc[0][1]);
        acc[0][2] = fmaf(xv.x, wv.z, acc[0][2]);
        acc[0][3] = fmaf(xv.x, wv.w, acc[0][3]);
        acc[1][0] = fmaf(xv.y, wv.x, acc[1][0]);
        acc[1][1] = fmaf(xv.y, wv.y, acc[1][1]);
        acc[1][2] = fmaf(xv.y, wv.z, acc[1][2]);
        acc[1][3] = fmaf(xv.y, wv.w, acc[1][3]);
        acc[2][0] = fmaf(xv.z, wv.x, acc[2][0]);
        acc[2][1] = fmaf(xv.z, wv.y, acc[2][1]);
        acc[2][2] = fmaf(xv.z, wv.z, acc[2][2]);
        acc[2][3] = fmaf(xv.z, wv.w, acc[2][3]);
        acc[3][0] = fmaf(xv.w, wv.x, acc[3][0]);
        acc[3][1] = fmaf(xv.w, wv.y, acc[3][1]);
        acc[3][2] = fmaf(xv.w, wv.z, acc[3][2]);
        acc[3][3] = fmaf(xv.w, wv.w, acc[3][3]);
    }
#pragma unroll
    for (int i = 0; i < 4; ++i) {
        int node = n0 + tr * 4 + i;
        if (node < N) {
            __hip_bfloat162 p0, p1;
            p0.x = __float2bfloat16(acc[i][0]);
            p0.y = __float2bfloat16(acc[i][1]);
            p1.x = __float2bfloat16(acc[i][2]);
            p1.y = __float2bfloat16(acc[i][3]);
            __hip_bfloat162* dst2 = (__hip_bfloat162*)&xW[(size_t)node * 64 + tc * 4];
            dst2[0] = p0;
            dst2[1] = p1;
        }
    }
}

// ---------------- conv1 gather (MLP-8) + relu + 64->2 projection ----------------
__global__ __launch_bounds__(256) void k_gather1(
        const bf16* __restrict__ xW, const float* __restrict__ dinv,
        const int* __restrict__ rp, const int* __restrict__ col,
        const float* __restrict__ b1, const float* __restrict__ U,
        float* __restrict__ Q, float* __restrict__ P, int N, int E) {
    int wid = (blockIdx.x * 256 + threadIdx.x) >> 6;
    int o = threadIdx.x & 63;
    if (wid >= N) return;
    float di = dinv[wid];
    float acc = di * __bfloat162float(xW[(size_t)wid * 64 + o]);
    int beg = rp[wid], end = rp[wid + 1];
    for (int base = beg; base < end; base += 64) {
        int nn = min(64, end - base);
        int colv = col[min(base + o, E - 1)];
        int jj = 0;
        for (; jj + 8 <= nn; jj += 8) {
            int m0 = __shfl(colv, jj + 0);
            int m1 = __shfl(colv, jj + 1);
            int m2 = __shfl(colv, jj + 2);
            int m3 = __shfl(colv, jj + 3);
            int m4 = __shfl(colv, jj + 4);
            int m5 = __shfl(colv, jj + 5);
            int m6 = __shfl(colv, jj + 6);
            int m7 = __shfl(colv, jj + 7);
            float w0 = dinv[m0], w1 = dinv[m1], w2 = dinv[m2], w3 = dinv[m3];
            float w4 = dinv[m4], w5 = dinv[m5], w6 = dinv[m6], w7 = dinv[m7];
            float v0 = __bfloat162float(xW[(size_t)m0 * 64 + o]);
            float v1 = __bfloat162float(xW[(size_t)m1 * 64 + o]);
            float v2 = __bfloat162float(xW[(size_t)m2 * 64 + o]);
            float v3 = __bfloat162float(xW[(size_t)m3 * 64 + o]);
            float v4 = __bfloat162float(xW[(size_t)m4 * 64 + o]);
            float v5 = __bfloat162float(xW[(size_t)m5 * 64 + o]);
            float v6 = __bfloat162float(xW[(size_t)m6 * 64 + o]);
            float v7 = __bfloat162float(xW[(size_t)m7 * 64 + o]);
            acc = fmaf(w0, v0, acc);
            acc = fmaf(w1, v1, acc);
            acc = fmaf(w2, v2, acc);
            acc = fmaf(w3, v3, acc);
            acc = fmaf(w4, v4, acc);
            acc = fmaf(w5, v5, acc);
            acc = fmaf(w6, v6, acc);
            acc = fmaf(w7, v7, acc);
        }
        for (; jj < nn; ++jj) {
            int m = __shfl(colv, jj);
            acc = fmaf(dinv[m], __bfloat162float(xW[(size_t)m * 64 + o]), acc);
        }
    }
    acc *= di;
    float h = fmaxf(acc + b1[o], 0.f);
    float q0 = h * U[o * 2 + 0];
    float q1 = h * U[o * 2 + 1];
#pragma unroll
    for (int mm = 32; mm; mm >>= 1) {
        q0 += __shfl_xor(q0, mm);
        q1 += __shfl_xor(q1, mm);
    }
    if (o == 0) {
        float d2 = di * di;
        Q[2 * wid + 0] = q0;      Q[2 * wid + 1] = q1;
        P[2 * wid + 0] = d2 * q0; P[2 * wid + 1] = d2 * q1;
    }
}

// ---------------- conv2 scalar gather ----------------
__global__ void k_gather2(const float* __restrict__ dinv, const int* __restrict__ rp,
                          const int* __restrict__ col, const float* __restrict__ Q,
                          float* __restrict__ P, int N) {
    int n = blockIdx.x * blockDim.x + threadIdx.x;
    if (n >= N) return;
    float di = dinv[n];
    float p0 = P[2 * n + 0], p1 = P[2 * n + 1];
    int beg = rp[n], end = rp[n + 1];
    for (int j = beg; j < end; ++j) {
        int m = col[j];
        float w = di * dinv[m];
        float2 q = ((const float2*)Q)[m];
        p0 = fmaf(w, q.x, p0);
        p1 = fmaf(w, q.y, p1);
    }
    P[2 * n + 0] = p0;
    P[2 * n + 1] = p1;
}

// ---------------- per-edge epilogue -> fp32 out ----------------
__global__ void k_edge(const int* __restrict__ src, const int* __restrict__ dst,
                       const int* __restrict__ attr, const float* __restrict__ P,
                       const float* __restrict__ E0t, const float* __restrict__ E1t,
                       const float* __restrict__ C, float* __restrict__ out, int E) {
    int e = blockIdx.x * blockDim.x + threadIdx.x;
    if (e >= E) return;
    int s = src[e], d = dst[e];
    float a0 = (float)attr[e];
    float a1 = (float)attr[E + e];
    int i2 = attr[2 * E + e], i3 = attr[3 * E + e];
    const float2* P2 = (const float2*)P;
    float2 ps = P2[s], pd = P2[d];
    float z0 = ps.x - pd.x + a0 * C[2] + a1 * C[4] + E0t[i2 * 2 + 0] + E1t[i3 * 2 + 0] + C[0];
    float z1 = ps.y - pd.y + a0 * C[3] + a1 * C[5] + E0t[i2 * 2 + 1] + E1t[i3 * 2 + 1] + C[1];
    float r0 = fmaxf(z0, 0.f), r1 = fmaxf(z1, 0.f);
    float o0 = r0 * C[6] + r1 * C[8] + C[10];
    float o1 = r0 * C[7] + r1 * C[9] + C[11];
    float m = fmaxf(o0, o1);
    float lse = m + logf(expf(o0 - m) + expf(o1 - m));
    float2 res;
    res.x = o0 - lse;
    res.y = o1 - lse;
    ((float2*)out)[e] = res;
}

extern "C" void kernel_launch(void* const* d_in, const int* in_sizes, int n_in,
                              void* d_out, int out_size, void* d_ws, size_t ws_size,
                              hipStream_t stream) {
    const float* x    = (const float*)d_in[0];
    const int*   ei   = (const int*)d_in[1];
    const int*   ea   = (const int*)d_in[2];
    const float* W1   = (const float*)d_in[3];
    const float* b1   = (const float*)d_in[4];
    const float* W2   = (const float*)d_in[5];
    const float* emb0 = (const float*)d_in[7];
    const float* emb1 = (const float*)d_in[8];
    const float* fcW1 = (const float*)d_in[9];
    const float* fcb1 = (const float*)d_in[10];
    const float* fcW2 = (const float*)d_in[11];
    const float* fcb2 = (const float*)d_in[12];

    const int N = in_sizes[0] / 64;
    const int E = in_sizes[1] / 2;
    const int* src = ei;
    const int* dst = ei + E;
    const int NB = (N + 255) >> 8;                // buckets of 256 nodes (391)
    const int NBB = NB * NBLK;                    // count-matrix size (100096)
    const int chunk = (E + NBLK - 1) / NBLK;      // edges per kA/kB block
    const int BS = (NBB + 255) / 256;             // scan blocks (391 <= 512)

    // ws layout (4-byte words), ~15.6 MB:
    char* wsb = (char*)d_ws;
    float* dinv = (float*)wsb;                             // N
    int*   rp   = (int*)(wsb + (size_t)4 * 100352);        // N+1
    int*   cntm = (int*)(wsb + (size_t)4 * 200704);        // NBB (=100096)
    int*   part = (int*)(wsb + (size_t)4 * 300800);        // 512
    float* U    = (float*)(wsb + (size_t)4 * 301312);      // 128
    float* E0t  = U + 128;                                 // 40
    float* E1t  = E0t + 40;                                // 40
    float* C    = E1t + 40;                                // 12
    float* Q    = (float*)(wsb + (size_t)4 * 301568);      // 2N
    float* P    = (float*)(wsb + (size_t)4 * 501760);      // 2N
    bf16*  xW   = (bf16*)(wsb + (size_t)4 * 702464);       // N*64 bf16 (12.8 MB)
    int*   col   = (int*)d_out;                            // E ints (first half)
    int*   pairs = (int*)d_out + E;                        // E ints (second half)
    // col+pairs = 2E ints = exactly out_size floats; k_edge overwrites last.

    k_small<<<1, 64, 0, stream>>>(W2, emb0, emb1, fcW1, fcb1, fcW2, fcb2,
                                  U, E0t, E1t, C);
    kA<<<NBLK, 256, 0, stream>>>(dst, cntm, E, chunk, NB);
    k_mscan1<<<BS, 256, 0, stream>>>(cntm, part, NBB);
    k_scan2<<<1, 512, 0, stream>>>(part, BS);
    k_mscan3<<<BS, 256, 0, stream>>>(cntm, part, NBB);
    kB<<<NBLK, 256, 0, stream>>>(src, dst, cntm, pairs, E, chunk, NB);
    kC<<<NB, 256, 0, stream>>>(cntm, pairs, col, rp, dinv, N, E, NB);
    k_gemm1<<<(N + 63) / 64, 256, 0, stream>>>(x, W1, xW, N);
    k_gather1<<<((size_t)N * 64 + 255) / 256, 256, 0, stream>>>(xW, dinv, rp, col, b1, U, Q, P, N, E);
    k_gather2<<<(N + 255) / 256, 256, 0, stream>>>(dinv, rp, col, Q, P, N);
    k_edge<<<(E + 255) / 256, 256, 0, stream>>>(src, dst, ea, P, E0t, E1t, C,
                                                (float*)d_out, E);
}